// Round 3
// baseline (2118.510 us; speedup 1.0000x reference)
//
#include <hip/hip_runtime.h>

// VQ embedding, filter+rescue design.
//  K1 esq:    e_sq f32 (f64-accum), max||e||^2, zero counters
//  K2 cvt:    codebook f32 -> f16 (g_cb16, linear)
//  K3 filter: f16 MFMA scores s~ = esq - 2*(z~.e~); sweep1 per-query min,
//             sweep2 candidates within rigorous margin; single-candidate
//             queries finalized (idx + z_q gather); multi-candidate queries
//             flagged, candidate pairs appended.
//  K4 rescue: per pair, bit-exact numpy-SSE f32 score; atomicMin packed
//             (sortable_score, k) per query  (tie -> lowest k).
//  K5 final:  flagged queries: write idx + z_q from winning k.
// Exact arithmetic identical to the verified round-2 kernel (absmax 0).

#define NQ  131072
#define Dq  256
#define Kn  1024
#define QTb 128                // queries per filter block
#define CH  64                 // codes per k-chunk
#define CAP (4*1024*1024)

typedef _Float16 half8 __attribute__((ext_vector_type(8)));
typedef float f32x4 __attribute__((ext_vector_type(4)));
typedef unsigned long long u64;
typedef unsigned int u32;

__device__ _Float16 g_cb16[Kn * Dq];
__device__ float    g_es32[Kn];
__device__ float    g_zsq[NQ];
__device__ int      g_esqmax_bits;     // monotone across launches
__device__ int      g_counts[2];       // [0]=pairs, [1]=flagged
__device__ u32      g_pairs[CAP];
__device__ u32      g_flag[NQ];
__device__ u64      g_slot[NQ];

__device__ __forceinline__ u32 fkey(float s) {
    u32 b = __float_as_uint(s);
    return (b & 0x80000000u) ? ~b : (b | 0x80000000u);
}

__global__ void esq_kernel(const float* __restrict__ cb) {
    int k = blockIdx.x * blockDim.x + threadIdx.x;
    if (k == 0) { g_counts[0] = 0; g_counts[1] = 0; }
    if (k < Kn) {
        const float* row = cb + (size_t)k * Dq;
        double s = 0.0;
        #pragma unroll 8
        for (int d = 0; d < Dq; ++d) { double v = (double)row[d]; s = fma(v, v, s); }
        float f = (float)s;
        g_es32[k] = f;
        atomicMax(&g_esqmax_bits, __float_as_int(f));
    }
}

__global__ void cvt_kernel(const float* __restrict__ cb) {
    int id = blockIdx.x * blockDim.x + threadIdx.x;   // 32768 chunks of 8
    if (id < Kn * Dq / 8) {
        const float* src = cb + (size_t)id * 8;
        union { _Float16 h[8]; uint4 v; } u;
        #pragma unroll
        for (int j = 0; j < 8; ++j) u.h[j] = (_Float16)src[j];
        *(uint4*)(g_cb16 + (size_t)id * 8) = u.v;
    }
}

__global__ __launch_bounds__(512, 4) void filter_kernel(
        const float* __restrict__ z, const float* __restrict__ cb,
        float* __restrict__ zq, float* __restrict__ idxo) {
    __shared__ _Float16 cs[2][CH * Dq];      // 2 x 32 KiB, swizzled rows
    __shared__ float zsq_sh[QTb];
    __shared__ int   finalk_sh[QTb];

    const int t    = threadIdx.x;
    const int wave = t >> 6;
    const int lane = t & 63;
    const int row  = lane & 15;              // k-lane / z-row
    const int g4   = lane >> 4;              // 0..3
    const int q0b  = blockIdx.x * QTb;
    const int q0w  = q0b + wave * 16;

    // ---- load z rows -> f16 A-fragments (VGPR-resident) + exact zsq ----
    half8 za[8];
    double zsqp = 0.0;
    #pragma unroll
    for (int s = 0; s < 8; ++s) {
        const float* zp = z + (size_t)(q0w + row) * Dq + s * 32 + g4 * 8;
        float4 v0 = *(const float4*)zp;
        float4 v1 = *(const float4*)(zp + 4);
        half8 h;
        h[0]=(_Float16)v0.x; h[1]=(_Float16)v0.y; h[2]=(_Float16)v0.z; h[3]=(_Float16)v0.w;
        h[4]=(_Float16)v1.x; h[5]=(_Float16)v1.y; h[6]=(_Float16)v1.z; h[7]=(_Float16)v1.w;
        za[s] = h;
        zsqp = fma((double)v0.x, (double)v0.x, zsqp);
        zsqp = fma((double)v0.y, (double)v0.y, zsqp);
        zsqp = fma((double)v0.z, (double)v0.z, zsqp);
        zsqp = fma((double)v0.w, (double)v0.w, zsqp);
        zsqp = fma((double)v1.x, (double)v1.x, zsqp);
        zsqp = fma((double)v1.y, (double)v1.y, zsqp);
        zsqp = fma((double)v1.z, (double)v1.z, zsqp);
        zsqp = fma((double)v1.w, (double)v1.w, zsqp);
    }
    zsqp += __shfl_xor(zsqp, 16);
    zsqp += __shfl_xor(zsqp, 32);
    float zsq32 = (float)zsqp;
    if (g4 == 0) { g_zsq[q0w + row] = zsq32; zsq_sh[wave * 16 + row] = zsq32; }
    __syncthreads();

    const float emax = sqrtf(__int_as_float(g_esqmax_bits));
    float marg[4], thr[4], mn[4];
    int cnt[4], lastk[4];
    #pragma unroll
    for (int r = 0; r < 4; ++r) {
        marg[r] = 3.90625e-3f * sqrtf(zsq_sh[wave * 16 + g4 * 4 + r]) * emax + 1.5e-4f;
        mn[r] = 3.4e38f; thr[r] = 3.4e38f; cnt[r] = 0; lastk[r] = -1;
    }

    // ---- prologue stage chunk 0 -> buf 0 ----
    {
        #pragma unroll
        for (int i = 0; i < 4; ++i) {
            int id = t + i * 512, kl = id >> 5, col = id & 31;
            uint4 v = *(const uint4*)(g_cb16 + (size_t)kl * Dq + col * 8);
            int dstb = kl * 512 + ((col * 16) ^ ((kl & 7) << 4));
            *(uint4*)((char*)cs[0] + dstb) = v;
        }
    }

    for (int cc = 0; cc < 32; ++cc) {
        const int b = cc & 1;
        const int c = cc & 15;
        const bool sweep2 = cc >= 16;
        __syncthreads();                     // staged buf b ready; prev reads done

        // issue next-chunk global loads (held in regs across MFMA)
        uint4 st[4]; int sd[4];
        const bool do_stage = cc < 31;
        if (do_stage) {
            int cn = (cc + 1) & 15;
            #pragma unroll
            for (int i = 0; i < 4; ++i) {
                int id = t + i * 512, kl = id >> 5, col = id & 31;
                st[i] = *(const uint4*)(g_cb16 + (size_t)(cn * CH + kl) * Dq + col * 8);
                sd[i] = kl * 512 + ((col * 16) ^ ((kl & 7) << 4));
            }
        }

        // MFMA: 16q x 64k x 256d
        f32x4 acc[4];
        #pragma unroll
        for (int kt = 0; kt < 4; ++kt) acc[kt] = (f32x4)0.0f;
        #pragma unroll
        for (int s = 0; s < 8; ++s) {
            #pragma unroll
            for (int kt = 0; kt < 4; ++kt) {
                int kl = kt * 16 + row;
                int byte = kl * 512 + (((s * 64) + g4 * 16) ^ ((kl & 7) << 4));
                half8 bf = *(const half8*)((const char*)cs[b] + byte);
                acc[kt] = __builtin_amdgcn_mfma_f32_16x16x32_f16(za[s], bf, acc[kt], 0, 0, 0);
            }
        }

        // fold scores
        #pragma unroll
        for (int kt = 0; kt < 4; ++kt) {
            int kg = c * CH + kt * 16 + row;
            float es = g_es32[kg];
            #pragma unroll
            for (int r = 0; r < 4; ++r) {
                float sg = es - 2.0f * acc[kt][r];
                if (!sweep2) {
                    mn[r] = fminf(mn[r], sg);
                } else if (sg <= thr[r]) {
                    cnt[r]++; lastk[r] = kg;
                    int qg = q0w + g4 * 4 + r;
                    int ix = atomicAdd(&g_counts[0], 1);
                    if (ix < CAP) g_pairs[ix] = ((u32)qg << 10) | (u32)kg;
                }
            }
        }

        // write staged chunk to other buffer
        if (do_stage) {
            #pragma unroll
            for (int i = 0; i < 4; ++i)
                *(uint4*)((char*)cs[b ^ 1] + sd[i]) = st[i];
        }

        if (cc == 15) {                       // end sweep1: reduce mins over k-lanes
            #pragma unroll
            for (int r = 0; r < 4; ++r) {
                float m = mn[r];
                m = fminf(m, __shfl_xor(m, 1));
                m = fminf(m, __shfl_xor(m, 2));
                m = fminf(m, __shfl_xor(m, 4));
                m = fminf(m, __shfl_xor(m, 8));
                thr[r] = m + marg[r];
                cnt[r] = 0; lastk[r] = -1;
            }
        }
    }

    // reduce candidate counts over the 16 k-lanes
    #pragma unroll
    for (int r = 0; r < 4; ++r) {
        int c2 = cnt[r], kk = lastk[r];
        #pragma unroll
        for (int m = 1; m <= 8; m <<= 1) {
            c2 += __shfl_xor(c2, m);
            kk = max(kk, __shfl_xor(kk, m));
        }
        if (row == 0) finalk_sh[wave * 16 + g4 * 4 + r] = (c2 <= 1) ? kk : -1;
    }
    __syncthreads();

    // finalize: unflagged -> write idx + gather z_q; flagged -> init slot, append
    {
        int ql = t >> 2, r = t & 3;
        int fk = finalk_sh[ql];
        int qg = q0b + ql;
        if (fk >= 0) {
            if (r == 0) idxo[qg] = (float)fk;
            const float4* src = (const float4*)(cb + (size_t)fk * Dq);
            float4* dst = (float4*)(zq + (size_t)qg * Dq);
            #pragma unroll
            for (int i = 0; i < 16; ++i) dst[i * 4 + r] = src[i * 4 + r];
        } else if (r == 0) {
            g_slot[qg] = ~0ull;
            int fi = atomicAdd(&g_counts[1], 1);
            g_flag[fi] = (u32)qg;
        }
    }
}

__global__ __launch_bounds__(256) void rescue_kernel(
        const float* __restrict__ z, const float* __restrict__ cb) {
    int n = g_counts[0]; if (n > CAP) n = CAP;
    const int wid  = (blockIdx.x * blockDim.x + threadIdx.x) >> 6;
    const int nw   = (gridDim.x * blockDim.x) >> 6;
    const int lane = threadIdx.x & 63;
    const int sub  = lane >> 2, j = lane & 3;
    for (int base = wid * 16; base < n; base += nw * 16) {
        int p = base + sub;
        bool valid = p < n;
        u32 enc = valid ? g_pairs[p] : 0u;
        int q = enc >> 10, k = enc & 1023;
        const float* zr = z + (size_t)q * Dq;
        const float* cr = cb + (size_t)k * Dq;
        float sj = 0.0f;
        {
            #pragma clang fp contract(off)
            #pragma unroll 8
            for (int i = 0; i < 64; ++i) {      // numpy SSE lane j: d = 4i+j
                float a = zr[4 * i + j];
                float bb = cr[4 * i + j];
                float pr = a * bb;
                sj = sj + pr;
            }
            float a1  = sj + __shfl_xor(sj, 1);     // (s0+s1),(s2+s3)
            float cr2 = a1 + __shfl_xor(a1, 2);     // (s0+s1)+(s2+s3)
            if (j == 0 && valid) {
                float t1 = g_zsq[q] + g_es32[k];
                float sc = t1 - 2.0f * cr2;
                u64 pk = ((u64)fkey(sc) << 32) | (u64)(u32)k;
                atomicMin(&g_slot[q], pk);
            }
        }
    }
}

__global__ __launch_bounds__(256) void final_kernel(
        const float* __restrict__ cb, float* __restrict__ zq,
        float* __restrict__ idxo) {
    int m = g_counts[1]; if (m > NQ) m = NQ;
    const int wid  = (blockIdx.x * blockDim.x + threadIdx.x) >> 6;
    const int nw   = (gridDim.x * blockDim.x) >> 6;
    const int lane = threadIdx.x & 63;
    for (int i = wid; i < m; i += nw) {
        int q = (int)g_flag[i];
        u64 sv = g_slot[q];
        int k = (int)(u32)sv;
        if (lane == 0) idxo[q] = (float)k;
        float4 v = ((const float4*)(cb + (size_t)k * Dq))[lane];
        ((float4*)(zq + (size_t)q * Dq))[lane] = v;
    }
}

extern "C" void kernel_launch(void* const* d_in, const int* in_sizes, int n_in,
                              void* d_out, int out_size, void* d_ws, size_t ws_size,
                              hipStream_t stream) {
    const float* z  = (const float*)d_in[0];
    const float* cb = (const float*)d_in[1];
    float* out = (float*)d_out;
    int nz = in_sizes[0];
    int nq = nz / Dq;
    float* zqp  = out;
    float* idxo = out + (size_t)nz;

    esq_kernel<<<4, 256, 0, stream>>>(cb);
    cvt_kernel<<<128, 256, 0, stream>>>(cb);
    filter_kernel<<<nq / QTb, 512, 0, stream>>>(z, cb, zqp, idxo);
    rescue_kernel<<<256, 256, 0, stream>>>(z, cb);
    final_kernel<<<64, 256, 0, stream>>>(cb, zqp, idxo);
}

// Round 4
// 450.431 us; speedup vs baseline: 4.7033x; 4.7033x over previous
//
#include <hip/hip_runtime.h>

// VQ embedding, filter + in-kernel rescue (no global atomics in hot path).
//  K1 esq:    e_sq f32 (f64-accum) + max||e||^2
//  K2 cvt:    codebook f32 -> f16
//  K3 filter: sweep1 f16-MFMA per-query min; sweep2 appends candidates within
//             a rigorous error margin to a PER-WAVE LDS list (LDS atomics);
//             per-wave exact rescore (bit-exact numpy-SSE f32), per-query min
//             with lowest-k tie-break; block writes idx + gathers z_q.
// Exact arithmetic identical to the verified round-2/3 kernels (absmax 0).

#define NQ   131072
#define Dq   256
#define Kn   1024
#define QTb  128               // queries per block (8 waves x 16)
#define CH   64                // codes per k-chunk
#define WCAP 96                // per-wave candidate cap (expected ~19)

typedef _Float16 half8 __attribute__((ext_vector_type(8)));
typedef float f32x4 __attribute__((ext_vector_type(4)));
typedef unsigned long long u64;
typedef unsigned int u32;

__device__ _Float16 g_cb16[Kn * Dq];
__device__ float    g_es32[Kn];
__device__ int      g_esqmax_bits;     // monotone across launches (same input)

__device__ __forceinline__ u32 fkey(float s) {
    u32 b = __float_as_uint(s);
    return (b & 0x80000000u) ? ~b : (b | 0x80000000u);
}

__global__ void esq_kernel(const float* __restrict__ cb) {
    int k = blockIdx.x * blockDim.x + threadIdx.x;
    if (k < Kn) {
        const float* row = cb + (size_t)k * Dq;
        double s = 0.0;
        #pragma unroll 8
        for (int d = 0; d < Dq; ++d) { double v = (double)row[d]; s = fma(v, v, s); }
        float f = (float)s;
        g_es32[k] = f;
        atomicMax(&g_esqmax_bits, __float_as_int(f));
    }
}

__global__ void cvt_kernel(const float* __restrict__ cb) {
    int id = blockIdx.x * blockDim.x + threadIdx.x;
    if (id < Kn * Dq / 8) {
        const float* src = cb + (size_t)id * 8;
        union { _Float16 h[8]; uint4 v; } u;
        #pragma unroll
        for (int j = 0; j < 8; ++j) u.h[j] = (_Float16)src[j];
        *(uint4*)(g_cb16 + (size_t)id * 8) = u.v;
    }
}

__global__ __launch_bounds__(512, 4) void filter_kernel(
        const float* __restrict__ z, const float* __restrict__ cb,
        float* __restrict__ zq, float* __restrict__ idxo) {
    __shared__ _Float16 cs[2][CH * Dq];   // 65536 B, swizzled rows
    __shared__ float zsq_sh[QTb];         // 512 B
    __shared__ int   win_sh[QTb];         // 512 B
    __shared__ u32   enc_sh[8][WCAP];     // 3072 B
    __shared__ u64   pk_sh[8][WCAP];      // 6144 B
    __shared__ int   wcnt[8];             // 32 B   total ~75.8 KiB -> 2 blk/CU

    const int t    = threadIdx.x;
    const int wave = t >> 6;
    const int lane = t & 63;
    const int row  = lane & 15;           // k-lane / z-row
    const int g4   = lane >> 4;           // 0..3
    const int q0b  = blockIdx.x * QTb;
    const int q0w  = q0b + wave * 16;

    if (t < 8) wcnt[t] = 0;

    // ---- z rows -> f16 A-fragments (VGPR) + exact f64 zsq ----
    half8 za[8];
    double zsqp = 0.0;
    #pragma unroll
    for (int s = 0; s < 8; ++s) {
        const float* zp = z + (size_t)(q0w + row) * Dq + s * 32 + g4 * 8;
        float4 v0 = *(const float4*)zp;
        float4 v1 = *(const float4*)(zp + 4);
        half8 h;
        h[0]=(_Float16)v0.x; h[1]=(_Float16)v0.y; h[2]=(_Float16)v0.z; h[3]=(_Float16)v0.w;
        h[4]=(_Float16)v1.x; h[5]=(_Float16)v1.y; h[6]=(_Float16)v1.z; h[7]=(_Float16)v1.w;
        za[s] = h;
        zsqp = fma((double)v0.x, (double)v0.x, zsqp);
        zsqp = fma((double)v0.y, (double)v0.y, zsqp);
        zsqp = fma((double)v0.z, (double)v0.z, zsqp);
        zsqp = fma((double)v0.w, (double)v0.w, zsqp);
        zsqp = fma((double)v1.x, (double)v1.x, zsqp);
        zsqp = fma((double)v1.y, (double)v1.y, zsqp);
        zsqp = fma((double)v1.z, (double)v1.z, zsqp);
        zsqp = fma((double)v1.w, (double)v1.w, zsqp);
    }
    zsqp += __shfl_xor(zsqp, 16);
    zsqp += __shfl_xor(zsqp, 32);
    if (g4 == 0) zsq_sh[wave * 16 + row] = (float)zsqp;
    __syncthreads();

    const float emax = sqrtf(__int_as_float(g_esqmax_bits));
    float marg[4], thr[4], mn[4];
    #pragma unroll
    for (int r = 0; r < 4; ++r) {
        marg[r] = 3.90625e-3f * sqrtf(zsq_sh[wave * 16 + g4 * 4 + r]) * emax + 1.5e-4f;
        mn[r] = 3.4e38f; thr[r] = 3.4e38f;
    }

    // prologue: stage chunk 0 -> buf 0
    #pragma unroll
    for (int i = 0; i < 4; ++i) {
        int id = t + i * 512, kl = id >> 5, col = id & 31;
        uint4 v = *(const uint4*)(g_cb16 + (size_t)kl * Dq + col * 8);
        int dstb = kl * 512 + ((col * 16) ^ ((kl & 7) << 4));
        *(uint4*)((char*)cs[0] + dstb) = v;
    }

    for (int cc = 0; cc < 32; ++cc) {
        const int b = cc & 1;
        const int c = cc & 15;
        const bool sweep2 = cc >= 16;
        __syncthreads();

        uint4 st[4]; int sd[4];
        const bool do_stage = cc < 31;
        if (do_stage) {
            int cn = (cc + 1) & 15;
            #pragma unroll
            for (int i = 0; i < 4; ++i) {
                int id = t + i * 512, kl = id >> 5, col = id & 31;
                st[i] = *(const uint4*)(g_cb16 + (size_t)(cn * CH + kl) * Dq + col * 8);
                sd[i] = kl * 512 + ((col * 16) ^ ((kl & 7) << 4));
            }
        }

        // MFMA: 16q x 64k x 256d
        f32x4 acc[4];
        #pragma unroll
        for (int kt = 0; kt < 4; ++kt) acc[kt] = (f32x4)0.0f;
        #pragma unroll
        for (int s = 0; s < 8; ++s) {
            #pragma unroll
            for (int kt = 0; kt < 4; ++kt) {
                int kl = kt * 16 + row;
                int byte = kl * 512 + (((s * 64) + g4 * 16) ^ ((kl & 7) << 4));
                half8 bf = *(const half8*)((const char*)cs[b] + byte);
                acc[kt] = __builtin_amdgcn_mfma_f32_16x16x32_f16(za[s], bf, acc[kt], 0, 0, 0);
            }
        }

        // fold
        #pragma unroll
        for (int kt = 0; kt < 4; ++kt) {
            int kg = c * CH + kt * 16 + row;
            float es = g_es32[kg];
            #pragma unroll
            for (int r = 0; r < 4; ++r) {
                float sg = es - 2.0f * acc[kt][r];
                if (!sweep2) {
                    mn[r] = fminf(mn[r], sg);
                } else if (sg <= thr[r]) {
                    int ix = atomicAdd(&wcnt[wave], 1);      // LDS atomic, wave-local
                    if (ix < WCAP)
                        enc_sh[wave][ix] = ((u32)(g4 * 4 + r) << 10) | (u32)kg;
                }
            }
        }

        if (do_stage) {
            #pragma unroll
            for (int i = 0; i < 4; ++i)
                *(uint4*)((char*)cs[b ^ 1] + sd[i]) = st[i];
        }

        if (cc == 15) {                    // end sweep1: min over 16 k-lanes
            #pragma unroll
            for (int r = 0; r < 4; ++r) {
                float m = mn[r];
                m = fminf(m, __shfl_xor(m, 1));
                m = fminf(m, __shfl_xor(m, 2));
                m = fminf(m, __shfl_xor(m, 4));
                m = fminf(m, __shfl_xor(m, 8));
                thr[r] = m + marg[r];
            }
        }
    }

    // ---- per-wave exact rescore (bit-exact numpy-SSE f32) ----
    int n = wcnt[wave];
    if (n > WCAP) n = WCAP;
    const int sub = lane >> 2, j = lane & 3;
    for (int base = 0; base < n; base += 16) {
        int p = base + sub;
        bool valid = p < n;
        u32 enc = valid ? enc_sh[wave][p] : 0u;
        int ql = enc >> 10, k = enc & 1023;
        const float* zr = z + (size_t)(q0w + ql) * Dq;
        const float* cr = cb + (size_t)k * Dq;
        float sj = 0.0f;
        {
            #pragma clang fp contract(off)
            #pragma unroll 8
            for (int i = 0; i < 64; ++i) {     // SSE lane j: d = 4i + j
                float a  = zr[4 * i + j];
                float bb = cr[4 * i + j];
                float pr = a * bb;
                sj = sj + pr;
            }
            float a1  = sj + __shfl_xor(sj, 1);    // (s0+s1),(s2+s3)
            float cr2 = a1 + __shfl_xor(a1, 2);    // (s0+s1)+(s2+s3)
            if (valid && j == 0) {
                float t1 = zsq_sh[wave * 16 + ql] + g_es32[k];
                float sc = t1 - 2.0f * cr2;
                pk_sh[wave][p] = ((u64)fkey(sc) << 32) | (u64)(u32)k;
            }
        }
    }
    // per-query min over this wave's list (tie -> lowest k via packed key)
    if (lane < 16) {
        u64 best = ~0ull;
        for (int i = 0; i < n; ++i) {
            if ((int)(enc_sh[wave][i] >> 10) == lane) {
                u64 v = pk_sh[wave][i];
                if (v < best) best = v;
            }
        }
        int kb = (int)(u32)best;
        win_sh[wave * 16 + lane] = kb;
        idxo[q0w + lane] = (float)kb;
    }
    __syncthreads();

    // gather z_q for all 128 queries (coalesced)
    #pragma unroll
    for (int i = 0; i < 16; ++i) {
        int id = t + i * 512;
        int ql = id >> 6, c = id & 63;
        float4 v = ((const float4*)(cb + (size_t)win_sh[ql] * Dq))[c];
        ((float4*)(zq + (size_t)(q0b + ql) * Dq))[c] = v;
    }
}

extern "C" void kernel_launch(void* const* d_in, const int* in_sizes, int n_in,
                              void* d_out, int out_size, void* d_ws, size_t ws_size,
                              hipStream_t stream) {
    const float* z  = (const float*)d_in[0];
    const float* cb = (const float*)d_in[1];
    float* out = (float*)d_out;
    int nz = in_sizes[0];
    int nq = nz / Dq;
    float* zqp  = out;
    float* idxo = out + (size_t)nz;

    esq_kernel<<<4, 256, 0, stream>>>(cb);
    cvt_kernel<<<128, 256, 0, stream>>>(cb);
    filter_kernel<<<nq / QTb, 512, 0, stream>>>(z, cb, zqp, idxo);
}